// Round 11
// baseline (482.178 us; speedup 1.0000x reference)
//
#include <hip/hip_runtime.h>
#include <hip/hip_bf16.h>

typedef unsigned short u16;
typedef unsigned int u32;
typedef short s8v __attribute__((ext_vector_type(8)));      // 8 bf16 bit-patterns
typedef float f32x16 __attribute__((ext_vector_type(16)));

constexpr int B = 4, L = 256, D = 256;
constexpr size_t SZ = (size_t)B * L * D;          // 262144

// Xt (transposed, padded): rows = spatial(-8..263) -> 272, cols = channel 0..255
constexpr int XROWS = 272;

// workspace offsets (floats)
constexpr size_t OFF_E    = 0;                        // 2*SZ fp32 e
constexpr size_t OFF_S    = 2 * SZ;                   // 262144 (raw sigmoid)
constexpr size_t OFF_EBF  = 3 * SZ;                   // 262144 (bf16 plane, 8 pb)
constexpr size_t OFF_XA   = 4 * SZ;                   // 278528
constexpr size_t OFF_XB   = OFF_XA + 278528;          // 278528
constexpr size_t OFF_WB   = OFF_XB + 278528;          // 786432 (single-plane conv W)
constexpr size_t OFF_WJ   = OFF_WB + 786432;          // 131072 (hi/lo ja weights)
constexpr size_t OFF_QK   = OFF_WJ + 131072;          // 262144
constexpr size_t OFF_BS   = OFF_QK + 262144;          // 256
constexpr size_t OFF_PP   = OFF_BS + 256;             // 524288
constexpr size_t OFF_POOL = OFF_PP + 524288;          // 1024
constexpr size_t OFF_F1P  = OFF_POOL + 1024;          // 76800
constexpr size_t OFF_H2   = OFF_F1P + 76800;          // 1200
constexpr size_t OFF_CNT  = OFF_H2 + 1200;            // 8 ints

// Wb layer offsets in ushorts (single plane: K q-planes of 65536)
constexpr size_t WB_L1 = 0;
constexpr size_t WB_L2 = (size_t)4 * 65536;
constexpr size_t WB_L3 = (size_t)12 * 65536;

__device__ __forceinline__ float sig_fast(float x) {
  return __fdividef(1.0f, 1.0f + __expf(-x));
}
__device__ __forceinline__ float lrelu(float x) { return x >= 0.0f ? x : 0.1f * x; }

__device__ __forceinline__ void split_bf16(float v, u16& h, u16& l) {
  __bf16 hb = (__bf16)v;
  float hf = (float)hb;
  __bf16 lb = (__bf16)(v - hf);
  h = __builtin_bit_cast(u16, hb);
  l = __builtin_bit_cast(u16, lb);
}
__device__ __forceinline__ u16 to_bf16(float v) {
  return __builtin_bit_cast(u16, (__bf16)v);
}

// ---- stage chaining: release-signal / acquire-spin (device scope) ----
__device__ __forceinline__ void signal_done(int* cnt) {
  __threadfence();
  __syncthreads();
  if (threadIdx.x == 0)
    __hip_atomic_fetch_add(cnt, 1, __ATOMIC_RELEASE, __HIP_MEMORY_SCOPE_AGENT);
}
__device__ __forceinline__ void spin_until(int* cnt, int target) {
  if (threadIdx.x == 0) {
    while (__hip_atomic_load(cnt, __ATOMIC_ACQUIRE, __HIP_MEMORY_SCOPE_AGENT) < target)
      __builtin_amdgcn_s_sleep(2);
    __threadfence();
  }
  __syncthreads();
}

// ---------------- fused prep: pad-zero + counters + weight prep + embed/transpose -------
__global__ __launch_bounds__(256) void k_prepall(const int* __restrict__ t1,
                                                 const int* __restrict__ t2,
                                                 const float* __restrict__ emb,
                                                 const float* __restrict__ w0,
                                                 const float* __restrict__ w1,
                                                 const float* __restrict__ w2,
                                                 const float* __restrict__ jw1,
                                                 const float* __restrict__ jw2,
                                                 u16* __restrict__ xa,
                                                 u16* __restrict__ xb,
                                                 u16* __restrict__ wb,
                                                 u16* __restrict__ wj,
                                                 int* __restrict__ cnt) {
  __shared__ float st[32][129];
  int blk = blockIdx.x;
  int t = threadIdx.x;
  if (blk < 64) {
    if (blk == 0 && t < 8) cnt[t] = 0;
    int gid = blk * 256 + t;                    // 0..16383
    int plane = gid >> 13, rem = gid & 8191;
    int pb = rem >> 10, rem2 = rem & 1023;
    int row16 = rem2 >> 6, cc = rem2 & 63;
    int row = row16 < 8 ? row16 : 256 + row16;
    u16* dst = plane ? xb : xa;
    *(ushort4*)(dst + (size_t)pb * (XROWS * 256) + (size_t)row * 256 + cc * 4) =
        make_ushort4(0, 0, 0, 0);
  } else if (blk < 896) {
    int b2 = blk - 64;                          // 0..831
    if (b2 < 768) {
      const float* w; u16* dst; int K, lblk;
      if (b2 < 128) { w = w0; dst = wb + WB_L1; K = 4; lblk = b2; }
      else if (b2 < 384) { w = w1; dst = wb + WB_L2; K = 8; lblk = b2 - 128; }
      else { w = w2; dst = wb + WB_L3; K = 12; lblk = b2 - 384; }
      int q = lblk >> 5, ig = lblk & 31, oc = t;
      union { u16 us[8]; uint4 v; } H;
#pragma unroll
      for (int e = 0; e < 8; ++e)
        H.us[e] = to_bf16(w[((size_t)oc * 256 + ig * 8 + e) * K + q]);
      *(uint4*)(dst + (size_t)q * 65536 + (size_t)ig * 2048 + (size_t)oc * 8) = H.v;
    } else {
      int lblk = b2 - 768;
      int kg = lblk & 31, p = lblk >> 5;
      const float* W = p ? jw2 : jw1;
      int n = t;
      union { u16 us[8]; uint4 v; } H, Lo;
#pragma unroll
      for (int e = 0; e < 8; ++e) {
        float v = W[(size_t)(kg * 8 + e) * 256 + n];
        split_bf16(v, H.us[e], Lo.us[e]);
      }
      size_t d = (size_t)(p * 2) * 65536 + ((size_t)kg * 256 + n) * 8;
      *(uint4*)(wj + d) = H.v;
      *(uint4*)(wj + d + 65536) = Lo.v;
    }
  } else {
    // embedding + transpose -> xa (single bf16 plane)
    int lb = blk - 896;                         // pb(3) lt(3) dt(1)
    int dt = lb & 1, lt = (lb >> 1) & 7, pb = lb >> 4;
    int l0 = lt * 32, d0 = dt * 128;
    const int* tok = (pb >> 2) ? t2 : t1;
    int c = t & 127, rq = t >> 7;
#pragma unroll 4
    for (int rr = 0; rr < 16; ++rr) {
      int r = rr * 2 + rq;
      int tv = tok[(pb & 3) * 256 + l0 + r];
      st[r][c] = emb[(size_t)tv * 256 + d0 + c];
    }
    __syncthreads();
    int dloc = t >> 1, lq = t & 1;
    size_t rbase = (size_t)pb * (XROWS * 256) + (size_t)(8 + d0 + dloc) * 256 + l0 + lq * 16;
#pragma unroll
    for (int lh = 0; lh < 4; ++lh) {
      u16 hb[4];
#pragma unroll
      for (int cc = 0; cc < 4; ++cc)
        hb[cc] = to_bf16(st[lq * 16 + lh * 4 + cc][dloc]);
      *(ushort4*)(xa + rbase + lh * 4) = make_ushort4(hb[0], hb[1], hb[2], hb[3]);
    }
  }
}

// ---------------- conv via MFMA: direct-global B, single-bf16 W, 1-barrier ----------------
template <int K, int P, int OUTMODE>
__global__ __launch_bounds__(256) void k_cmf(const u16* __restrict__ xh,
                                             const u16* __restrict__ wb,
                                             const float* __restrict__ bias,
                                             u16* __restrict__ yh,
                                             float* __restrict__ eout,
                                             u16* __restrict__ ebf) {
  __shared__ float cd[3072];            // waves 1..3 partials (12 KB)

  int blk = blockIdx.x;                 // pb(3) oct(3) jt(3)
  int jt = blk & 7, oct = (blk >> 3) & 7, pb = blk >> 6;
  int oc0 = oct * 32, j0 = jt * 32;
  int tid = threadIdx.x;
  int lane = tid & 63, wv = tid >> 6;
  int l31 = lane & 31, lhi = lane >> 5;

  f32x16 acc = {};
  size_t abase = (size_t)(oc0 + l31) * 8 + (size_t)(wv * 8 + lhi) * 2048;
  const u16* brow = xh + (size_t)pb * (XROWS * 256) +
                    (size_t)(j0 + l31 + 8 - P) * 256 + wv * 64 + lhi * 8;

  for (int q = 0; q < K; ++q) {
    const u16* bsrc = brow + (size_t)q * 256;
    size_t aq = (size_t)q * 65536 + abase;
#pragma unroll
    for (int ic = 0; ic < 4; ++ic) {
      s8v ah = *(const s8v*)(wb + aq + ic * 4096);
      s8v bh = *(const s8v*)(bsrc + ic * 16);
      acc = __builtin_amdgcn_mfma_f32_32x32x16_bf16(ah, bh, acc, 0, 0, 0);
    }
  }

  if (wv > 0) {
#pragma unroll
    for (int r = 0; r < 16; ++r) {
      int ocr = (r & 3) + 8 * (r >> 2) + 4 * lhi;
      cd[(wv - 1) * 1024 + ocr * 32 + l31] = acc[r];
    }
  }
  __syncthreads();
  if (wv == 0) {
    float v[16];
#pragma unroll
    for (int r = 0; r < 16; ++r) {
      int ocr = (r & 3) + 8 * (r >> 2) + 4 * lhi;
      int idx = ocr * 32 + l31;
      v[r] = fmaxf(acc[r] + cd[idx] + cd[1024 + idx] + cd[2048 + idx] + bias[oc0 + ocr], 0.0f);
    }
    if constexpr (OUTMODE == 0) {
      size_t ro = (size_t)pb * (XROWS * 256) + (size_t)(8 + j0 + l31) * 256 + oc0 + 4 * lhi;
#pragma unroll
      for (int rq = 0; rq < 4; ++rq) {
        *(ushort4*)(yh + ro + 8 * rq) =
            make_ushort4(to_bf16(v[rq * 4 + 0]), to_bf16(v[rq * 4 + 1]),
                         to_bf16(v[rq * 4 + 2]), to_bf16(v[rq * 4 + 3]));
      }
    } else {
#pragma unroll
      for (int r = 0; r < 16; ++r) {
        int ocr = (r & 3) + 8 * (r >> 2) + 4 * lhi;
        size_t eo = (size_t)pb * 65536 + (size_t)(oc0 + ocr) * 256 + j0 + l31;
        eout[eo] = v[r];
        ebf[((size_t)pb * 256 + oc0 + ocr) * 256 + j0 + l31] = to_bf16(v[r]);
      }
    }
  }
}

// ---------------- fused jam (512 blocks) + scores (256 blocks, spin-chained) ----------
__global__ __launch_bounds__(256) void k_js(const u16* __restrict__ ebf,
                                            const u16* __restrict__ wj,
                                            const float* __restrict__ b1,
                                            const float* __restrict__ b2,
                                            u16* __restrict__ qk,
                                            float* __restrict__ S,
                                            float* __restrict__ bsums,
                                            int* __restrict__ cnt) {
  __shared__ float cd[4128];
  int bid = blockIdx.x;
  int tid = threadIdx.x, wv = tid >> 6, lane = tid & 63;
  int l31 = lane & 31, lhi = lane >> 5;

  if (bid < 512) {
    // ---- jam: q/k projection ----
    int blk = bid;                      // pb(3) it(3) nt(3)
    int nt = blk & 7, it = (blk >> 3) & 7, pb = blk >> 6;
    int p = pb >> 2;
    int i0 = it * 32, n0 = nt * 32;

    const u16* eh = ebf + ((size_t)pb * 256 + i0 + l31) * 256 + lhi * 8;
    const u16* wjh = wj + (size_t)(p * 2) * 65536;

    f32x16 acc = {};
#pragma unroll
    for (int c = 0; c < 4; ++c) {
      int kc = wv * 4 + c;
      int kg = kc * 2 + lhi;
      s8v ah = *(const s8v*)(eh + kc * 16);
      s8v bh = *(const s8v*)(wjh + ((size_t)kg * 256 + n0 + l31) * 8);
      s8v bl = *(const s8v*)(wjh + 65536 + ((size_t)kg * 256 + n0 + l31) * 8);
      acc = __builtin_amdgcn_mfma_f32_32x32x16_bf16(ah, bh, acc, 0, 0, 0);
      acc = __builtin_amdgcn_mfma_f32_32x32x16_bf16(ah, bl, acc, 0, 0, 0);
    }

    if (wv > 0) {
#pragma unroll
      for (int r = 0; r < 16; ++r) {
        int row = (r & 3) + 8 * (r >> 2) + 4 * lhi;
        cd[(wv - 1) * 1024 + row * 32 + l31] = acc[r];
      }
    }
    __syncthreads();
    if (wv == 0) {
      float bv = (p ? b2 : b1)[n0 + l31];
#pragma unroll
      for (int r = 0; r < 16; ++r) {
        int row = (r & 3) + 8 * (r >> 2) + 4 * lhi;
        int idx = row * 32 + l31;
        cd[3072 + row * 33 + l31] = acc[r] + cd[idx] + cd[1024 + idx] + cd[2048 + idx] + bv;
      }
    }
    __syncthreads();

    int row = tid & 31, c8 = tid >> 5;
    u16 hb[4];
#pragma unroll
    for (int cc = 0; cc < 4; ++cc)
      hb[cc] = to_bf16(cd[3072 + row * 33 + c8 * 4 + cc]);
    size_t ro = ((size_t)pb * 256 + i0 + row) * 256 + n0 + c8 * 4;
    *(ushort4*)(qk + ro) = make_ushort4(hb[0], hb[1], hb[2], hb[3]);
    signal_done(&cnt[0]);
  } else {
    // ---- scores: wait for all q/k then sigmoid(q k^T) ----
    spin_until(&cnt[0], 512);
    int blk = bid - 512;                // b(2) it(3) jt(3)
    int jt = blk & 7, it = (blk >> 3) & 7, b = blk >> 6;
    int i0 = it * 32, j0 = jt * 32;

    const u16* qh = qk + ((size_t)b * 256 + i0 + l31) * 256 + lhi * 8;
    const u16* kh = qk + ((size_t)(4 + b) * 256 + j0 + l31) * 256 + lhi * 8;

    f32x16 acc = {};
#pragma unroll
    for (int c = 0; c < 4; ++c) {
      int kc = wv * 4 + c;
      s8v a = *(const s8v*)(qh + kc * 16);
      s8v bb = *(const s8v*)(kh + kc * 16);
      acc = __builtin_amdgcn_mfma_f32_32x32x16_bf16(a, bb, acc, 0, 0, 0);
    }

    if (wv > 0) {
#pragma unroll
      for (int r = 0; r < 16; ++r) {
        int row = (r & 3) + 8 * (r >> 2) + 4 * lhi;
        cd[(wv - 1) * 1024 + row * 32 + l31] = acc[r];
      }
    }
    __syncthreads();
    if (wv == 0) {
      float psum = 0.0f;
#pragma unroll
      for (int r = 0; r < 16; ++r) {
        int row = (r & 3) + 8 * (r >> 2) + 4 * lhi;
        int idx = row * 32 + l31;
        float s = sig_fast(acc[r] + cd[idx] + cd[1024 + idx] + cd[2048 + idx]);
        psum += s;
        cd[3072 + row * 33 + l31] = s;
      }
      for (int off = 32; off; off >>= 1) psum += __shfl_down(psum, off, 64);
      if (lane == 0) bsums[blk] = psum;
    }
    __syncthreads();

    int row = tid & 31, c8 = tid >> 5;
    float4 v;
    v.x = cd[3072 + row * 33 + c8 * 4 + 0];
    v.y = cd[3072 + row * 33 + c8 * 4 + 1];
    v.z = cd[3072 + row * 33 + c8 * 4 + 2];
    v.w = cd[3072 + row * 33 + c8 * 4 + 3];
    *(float4*)(S + ((size_t)b * 256 + i0 + row) * 256 + j0 + c8 * 4) = v;
  }
}

// ---------------- fused tail: pool -> poolcomb -> fc1(+head) -> fc2 -> fc3 ------------
__global__ __launch_bounds__(256) void k_tail(const float* __restrict__ e1,
                                              const float* __restrict__ e2,
                                              const float* __restrict__ S,
                                              const float* __restrict__ bsums,
                                              float* __restrict__ inter_out,
                                              float* __restrict__ pp,
                                              float* __restrict__ pooled,
                                              const float* __restrict__ rcw,
                                              const float* __restrict__ rcb,
                                              const float* __restrict__ fc1w,
                                              float* __restrict__ f1p,
                                              const float* __restrict__ fc1b,
                                              const float* __restrict__ fc2w,
                                              const float* __restrict__ fc2b,
                                              const float* __restrict__ fc3w,
                                              const float* __restrict__ fc3b,
                                              float* __restrict__ h2g,
                                              float* __restrict__ out,
                                              int* __restrict__ cnt) {
  __shared__ float sm[2408];
  int bid = blockIdx.x;
  int t = threadIdx.x;

  if (bid < 2048) {
    // ---- pool producer: one 8i x 16k tile ----
    int blk = bid;                      // b(2) ich(5) kch(4)
    int kch = blk & 15, ich = (blk >> 4) & 31, b = blk >> 9;
    int d = t, i0 = ich * 8, k0 = kch * 16;
    float* s2 = sm;                     // [kk*8+ii], 128
    float* red = sm + 128;              // 128
    int ii = t >> 4, kk = t & 15;
    float sv = 0.0f;
    if (t < 64) {
      float v = bsums[b * 64 + t];
      for (int off = 32; off; off >>= 1) v += __shfl_down(v, off, 64);
      if (t == 0) sm[257] = v;          // tot
    }
    if (t < 128) {
      sv = S[((size_t)(b * 256 + i0 + ii)) * 256 + k0 + kk];
      s2[kk * 8 + ii] = 2.0f * sv;
      red[t] = sv;
    }
    __syncthreads();
    for (int st = 64; st; st >>= 1) {
      if (t < st) red[t] += red[t + st];
      __syncthreads();
    }
    if (t == 0) sm[256] = red[0];       // ssp
    __syncthreads();

    float invt = 1.0f / sm[257];
    float ssp = sm[256];
    if (t < 128)
      inter_out[((size_t)(b * 256 + i0 + ii)) * 256 + k0 + kk] = sv * invt;

    constexpr float C2L = 2.8853900817779268f;   // 2*log2(e)
    float ev2[8];
#pragma unroll
    for (int i2 = 0; i2 < 8; ++i2)
      ev2[i2] = e1[((size_t)(b * L + i0 + i2)) * D + d] * C2L;

    float a0 = 0.f, a1 = 0.f, a2 = 0.f, a3 = 0.f;
    for (int k2 = 0; k2 < 16; ++k2) {
      float e2v = e2[((size_t)(b * L + k0 + k2)) * D + d];
      float s2r[8];
      *(float4*)&s2r[0] = *(const float4*)&s2[k2 * 8];
      *(float4*)&s2r[4] = *(const float4*)&s2[k2 * 8 + 4];
#pragma unroll
      for (int i2 = 0; i2 < 8; ++i2) {
        float r = __builtin_amdgcn_rcpf(__builtin_exp2f(ev2[i2] * e2v) + 1.0f);
        if ((i2 & 3) == 0) a0 = fmaf(r, s2r[i2], a0);
        else if ((i2 & 3) == 1) a1 = fmaf(r, s2r[i2], a1);
        else if ((i2 & 3) == 2) a2 = fmaf(r, s2r[i2], a2);
        else a3 = fmaf(r, s2r[i2], a3);
      }
    }
    float res = (ssp - (a0 + a1 + a2 + a3)) * invt;
    pp[(((size_t)b * 32 + ich) * 16 + kch) * 256 + d] = res;
    signal_done(&cnt[1]);
  } else if (bid < 2080) {
    // ---- poolcomb ----
    spin_until(&cnt[1], 2048);
    int s = bid - 2048;                 // b(2) dt(3)
    int dt = s & 7, b = s >> 3;
    int dl = t & 31, mg = t >> 5;
    int d = dt * 32 + dl;
    float acc = 0.f;
#pragma unroll
    for (int m = 0; m < 64; ++m)
      acc += pp[((size_t)b * 512 + mg * 64 + m) * 256 + d];
    sm[mg * 32 + dl] = acc;
    __syncthreads();
    if (mg == 0) {
      float tot = sm[dl] + sm[32 + dl] + sm[64 + dl] + sm[96 + dl] +
                  sm[128 + dl] + sm[160 + dl] + sm[192 + dl] + sm[224 + dl];
      pooled[b * 256 + d] = tot;
    }
    signal_done(&cnt[2]);
  } else if (bid < 2400) {
    // ---- fc1 with fused head conv+maxpool ----
    spin_until(&cnt[2], 32);
    int s = bid - 2080;
    int ich = s & 31, ot = s >> 5;
    float* spb = sm;                    // [4][258] = 1032
    float* hs = sm + 1032;              // [4][64]
#pragma unroll
    for (int ss = 0; ss < 4; ++ss) {
      int idx = ss * 256 + t;
      spb[(idx >> 8) * 258 + (idx & 255) + 1] = pooled[idx];
    }
    if (t < 4) { spb[t * 258] = 0.0f; spb[t * 258 + 257] = 0.0f; }
    __syncthreads();
    {
      int b = t >> 6, idx = t & 63;
      int c = ich * 2 + (idx >> 5), m = idx & 31;
      float w0 = rcw[c * 4 + 0], w1 = rcw[c * 4 + 1], w2 = rcw[c * 4 + 2], w3 = rcw[c * 4 + 3];
      float bias = rcb[c];
      float mx = -1e30f;
#pragma unroll
      for (int r = 0; r < 4; ++r) {
        int p2 = 2 * (4 * m + r);
        float y = bias;
        y = fmaf(w0, spb[b * 258 + p2], y);
        y = fmaf(w1, spb[b * 258 + p2 + 1], y);
        y = fmaf(w2, spb[b * 258 + p2 + 2], y);
        y = fmaf(w3, spb[b * 258 + p2 + 3], y);
        mx = fmaxf(mx, lrelu(y));
      }
      hs[b * 64 + idx] = mx;
    }
    __syncthreads();

    int ol = t & 63, b = t >> 6;
    int o = ot * 64 + ol;
    int oc_ = o < 600 ? o : 599;
    const float* wbp = fc1w + (size_t)(ich * 64) * 600 + oc_;
    float a0 = 0.f, a1 = 0.f, a2 = 0.f, a3 = 0.f;
#pragma unroll 4
    for (int i = 0; i < 64; i += 4) {
      a0 = fmaf(hs[b * 64 + i], wbp[(size_t)i * 600], a0);
      a1 = fmaf(hs[b * 64 + i + 1], wbp[(size_t)(i + 1) * 600], a1);
      a2 = fmaf(hs[b * 64 + i + 2], wbp[(size_t)(i + 2) * 600], a2);
      a3 = fmaf(hs[b * 64 + i + 3], wbp[(size_t)(i + 3) * 600], a3);
    }
    if (o < 600) f1p[((size_t)ich * 4 + b) * 600 + o] = a0 + a1 + a2 + a3;
    signal_done(&cnt[3]);
  } else if (bid < 2405) {
    // ---- fc2 (full-i): h1 combine in LDS, write h2 ----
    spin_until(&cnt[3], 320);
    int ot = bid - 2400;
    for (int e = t; e < 2400; e += 256) {
      int bb = e / 600, ii = e % 600;
      float s = fc1b[ii];
#pragma unroll
      for (int ich = 0; ich < 32; ++ich) s += f1p[((size_t)ich * 4 + bb) * 600 + ii];
      sm[bb * 601 + ii] = lrelu(s);
    }
    __syncthreads();
    int ol = t & 63, b = t >> 6;
    int o = ot * 64 + ol;
    if (o < 300) {
      const float* wbp = fc2w + o;
      float a0 = 0.f, a1 = 0.f, a2 = 0.f, a3 = 0.f;
#pragma unroll 2
      for (int ii = 0; ii < 600; ii += 4) {
        a0 = fmaf(sm[b * 601 + ii], wbp[(size_t)ii * 300], a0);
        a1 = fmaf(sm[b * 601 + ii + 1], wbp[(size_t)(ii + 1) * 300], a1);
        a2 = fmaf(sm[b * 601 + ii + 2], wbp[(size_t)(ii + 2) * 300], a2);
        a3 = fmaf(sm[b * 601 + ii + 3], wbp[(size_t)(ii + 3) * 300], a3);
      }
      h2g[b * 300 + o] = lrelu(fc2b[o] + a0 + a1 + a2 + a3);
    }
    signal_done(&cnt[4]);
  } else {
    // ---- fc3 ----
    spin_until(&cnt[4], 5);
    for (int e = t; e < 1200; e += 256) {
      int b = e / 300, o = e % 300;
      sm[b * 301 + o] = h2g[b * 300 + o];
    }
    __syncthreads();
    int wv = t >> 6, l = t & 63;
    if (wv < 4) {
      float s = 0.f;
#pragma unroll
      for (int m = 0; m < 5; ++m) {
        int i = m * 64 + l;
        if (i < 300) s = fmaf(sm[wv * 301 + i], fc3w[i], s);
      }
      for (int off = 32; off; off >>= 1) s += __shfl_down(s, off, 64);
      if (l == 0) out[262144 + wv] = s + fc3b[0];
    }
  }
}

extern "C" void kernel_launch(void* const* d_in, const int* in_sizes, int n_in,
                              void* d_out, int out_size, void* d_ws, size_t ws_size,
                              hipStream_t stream) {
  float* ws = (float*)d_ws;
  const int* p1 = (const int*)d_in[0];
  const int* p2 = (const int*)d_in[1];
  const float* emb  = (const float*)d_in[2];
  const float* w0   = (const float*)d_in[3];
  const float* b0   = (const float*)d_in[4];
  const float* w1   = (const float*)d_in[5];
  const float* b1   = (const float*)d_in[6];
  const float* w2   = (const float*)d_in[7];
  const float* b2   = (const float*)d_in[8];
  const float* ja1w = (const float*)d_in[9];
  const float* ja1b = (const float*)d_in[10];
  const float* ja2w = (const float*)d_in[11];
  const float* ja2b = (const float*)d_in[12];
  const float* rcw  = (const float*)d_in[13];
  const float* rcb  = (const float*)d_in[14];
  const float* fc1w = (const float*)d_in[15];
  const float* fc1b = (const float*)d_in[16];
  const float* fc2w = (const float*)d_in[17];
  const float* fc2b = (const float*)d_in[18];
  const float* fc3w = (const float*)d_in[19];
  const float* fc3b = (const float*)d_in[20];
  float* out = (float*)d_out;

  u16* xa  = (u16*)(ws + OFF_XA);
  u16* xb  = (u16*)(ws + OFF_XB);
  u16* wbu = (u16*)(ws + OFF_WB);
  u16* wju = (u16*)(ws + OFF_WJ);
  u16* ebf = (u16*)(ws + OFF_EBF);
  u16* qk  = (u16*)(ws + OFF_QK);
  int* cnt = (int*)(ws + OFF_CNT);

  k_prepall<<<1024, 256, 0, stream>>>(p1, p2, emb, w0, w1, w2, ja1w, ja2w, xa, xb, wbu, wju,
                                      cnt);

  k_cmf<4, 1, 0><<<512, 256, 0, stream>>>(xa, wbu + WB_L1, b0, xb, nullptr, nullptr);
  k_cmf<8, 3, 0><<<512, 256, 0, stream>>>(xb, wbu + WB_L2, b1, xa, nullptr, nullptr);
  k_cmf<12, 5, 1><<<512, 256, 0, stream>>>(xa, wbu + WB_L3, b2, nullptr, ws + OFF_E, ebf);

  k_js<<<768, 256, 0, stream>>>(ebf, wju, ja1b, ja2b, qk, ws + OFF_S, ws + OFF_BS, cnt);

  k_tail<<<2406, 256, 0, stream>>>(ws + OFF_E, ws + OFF_E + SZ, ws + OFF_S, ws + OFF_BS,
                                   out, ws + OFF_PP, ws + OFF_POOL, rcw, rcb,
                                   fc1w, ws + OFF_F1P, fc1b, fc2w, fc2b, fc3w, fc3b,
                                   ws + OFF_H2, out, cnt);
}

// Round 12
// 262.926 us; speedup vs baseline: 1.8339x; 1.8339x over previous
//
#include <hip/hip_runtime.h>
#include <hip/hip_bf16.h>

typedef unsigned short u16;
typedef unsigned int u32;
typedef short s8v __attribute__((ext_vector_type(8)));      // 8 bf16 bit-patterns
typedef float f32x16 __attribute__((ext_vector_type(16)));

constexpr int B = 4, L = 256, D = 256;
constexpr size_t SZ = (size_t)B * L * D;          // 262144

// Xt (transposed, padded): rows = spatial(-8..263) -> 272, cols = channel 0..255
constexpr int XROWS = 272;

// workspace offsets (floats)
constexpr size_t OFF_E    = 0;                        // 2*SZ fp32 e
constexpr size_t OFF_S    = 2 * SZ;                   // 262144 (raw sigmoid)
constexpr size_t OFF_EBF  = 3 * SZ;                   // 262144 (bf16 plane, 8 pb)
constexpr size_t OFF_XA   = 4 * SZ;                   // 278528
constexpr size_t OFF_XB   = OFF_XA + 278528;          // 278528
constexpr size_t OFF_WB   = OFF_XB + 278528;          // 786432 (single-plane conv W)
constexpr size_t OFF_WJ   = OFF_WB + 786432;          // 131072 (hi/lo ja weights)
constexpr size_t OFF_QK   = OFF_WJ + 131072;          // 262144
constexpr size_t OFF_BS   = OFF_QK + 262144;          // 256
constexpr size_t OFF_PP   = OFF_BS + 256;             // 524288
constexpr size_t OFF_POOL = OFF_PP + 524288;          // 1024
constexpr size_t OFF_F1P  = OFF_POOL + 1024;          // 76800
constexpr size_t OFF_H2   = OFF_F1P + 76800;          // 1200
constexpr size_t OFF_CNT  = OFF_H2 + 1200;            // 8 ints

// Wb layer offsets in ushorts (single plane: K q-planes of 65536)
constexpr size_t WB_L1 = 0;
constexpr size_t WB_L2 = (size_t)4 * 65536;
constexpr size_t WB_L3 = (size_t)12 * 65536;

__device__ __forceinline__ float sig_fast(float x) {
  return __fdividef(1.0f, 1.0f + __expf(-x));
}
__device__ __forceinline__ float lrelu(float x) { return x >= 0.0f ? x : 0.1f * x; }

__device__ __forceinline__ void split_bf16(float v, u16& h, u16& l) {
  __bf16 hb = (__bf16)v;
  float hf = (float)hb;
  __bf16 lb = (__bf16)(v - hf);
  h = __builtin_bit_cast(u16, hb);
  l = __builtin_bit_cast(u16, lb);
}
__device__ __forceinline__ u16 to_bf16(float v) {
  return __builtin_bit_cast(u16, (__bf16)v);
}

// ---- stage chaining, L2-friendly:
// signal: release fence (wbl2 writeback, NO invalidate) + relaxed atomic add.
// spin:   RELAXED agent loads (global_load sc1 — reads coherence point, NO
//         invalidate per poll), one acquire fence after the count is reached.
__device__ __forceinline__ void signal_done(int* cnt) {
  __syncthreads();
  if (threadIdx.x == 0) {
    __builtin_amdgcn_fence(__ATOMIC_RELEASE, "agent");
    __hip_atomic_fetch_add(cnt, 1, __ATOMIC_RELAXED, __HIP_MEMORY_SCOPE_AGENT);
  }
}
__device__ __forceinline__ void spin_until(int* cnt, int target) {
  if (threadIdx.x == 0) {
    while (__hip_atomic_load(cnt, __ATOMIC_RELAXED, __HIP_MEMORY_SCOPE_AGENT) < target)
      __builtin_amdgcn_s_sleep(8);
    __builtin_amdgcn_fence(__ATOMIC_ACQUIRE, "agent");
  }
  __syncthreads();
}

// ---------------- fused prep: pad-zero + counters + weight prep + embed/transpose -------
__global__ __launch_bounds__(256) void k_prepall(const int* __restrict__ t1,
                                                 const int* __restrict__ t2,
                                                 const float* __restrict__ emb,
                                                 const float* __restrict__ w0,
                                                 const float* __restrict__ w1,
                                                 const float* __restrict__ w2,
                                                 const float* __restrict__ jw1,
                                                 const float* __restrict__ jw2,
                                                 u16* __restrict__ xa,
                                                 u16* __restrict__ xb,
                                                 u16* __restrict__ wb,
                                                 u16* __restrict__ wj,
                                                 int* __restrict__ cnt) {
  __shared__ float st[32][129];
  int blk = blockIdx.x;
  int t = threadIdx.x;
  if (blk < 64) {
    if (blk == 0 && t < 8) cnt[t] = 0;
    int gid = blk * 256 + t;                    // 0..16383
    int plane = gid >> 13, rem = gid & 8191;
    int pb = rem >> 10, rem2 = rem & 1023;
    int row16 = rem2 >> 6, cc = rem2 & 63;
    int row = row16 < 8 ? row16 : 256 + row16;
    u16* dst = plane ? xb : xa;
    *(ushort4*)(dst + (size_t)pb * (XROWS * 256) + (size_t)row * 256 + cc * 4) =
        make_ushort4(0, 0, 0, 0);
  } else if (blk < 896) {
    int b2 = blk - 64;                          // 0..831
    if (b2 < 768) {
      const float* w; u16* dst; int K, lblk;
      if (b2 < 128) { w = w0; dst = wb + WB_L1; K = 4; lblk = b2; }
      else if (b2 < 384) { w = w1; dst = wb + WB_L2; K = 8; lblk = b2 - 128; }
      else { w = w2; dst = wb + WB_L3; K = 12; lblk = b2 - 384; }
      int q = lblk >> 5, ig = lblk & 31, oc = t;
      union { u16 us[8]; uint4 v; } H;
#pragma unroll
      for (int e = 0; e < 8; ++e)
        H.us[e] = to_bf16(w[((size_t)oc * 256 + ig * 8 + e) * K + q]);
      *(uint4*)(dst + (size_t)q * 65536 + (size_t)ig * 2048 + (size_t)oc * 8) = H.v;
    } else {
      int lblk = b2 - 768;
      int kg = lblk & 31, p = lblk >> 5;
      const float* W = p ? jw2 : jw1;
      int n = t;
      union { u16 us[8]; uint4 v; } H, Lo;
#pragma unroll
      for (int e = 0; e < 8; ++e) {
        float v = W[(size_t)(kg * 8 + e) * 256 + n];
        split_bf16(v, H.us[e], Lo.us[e]);
      }
      size_t d = (size_t)(p * 2) * 65536 + ((size_t)kg * 256 + n) * 8;
      *(uint4*)(wj + d) = H.v;
      *(uint4*)(wj + d + 65536) = Lo.v;
    }
  } else {
    // embedding + transpose -> xa (single bf16 plane)
    int lb = blk - 896;                         // pb(3) lt(3) dt(1)
    int dt = lb & 1, lt = (lb >> 1) & 7, pb = lb >> 4;
    int l0 = lt * 32, d0 = dt * 128;
    const int* tok = (pb >> 2) ? t2 : t1;
    int c = t & 127, rq = t >> 7;
#pragma unroll 4
    for (int rr = 0; rr < 16; ++rr) {
      int r = rr * 2 + rq;
      int tv = tok[(pb & 3) * 256 + l0 + r];
      st[r][c] = emb[(size_t)tv * 256 + d0 + c];
    }
    __syncthreads();
    int dloc = t >> 1, lq = t & 1;
    size_t rbase = (size_t)pb * (XROWS * 256) + (size_t)(8 + d0 + dloc) * 256 + l0 + lq * 16;
#pragma unroll
    for (int lh = 0; lh < 4; ++lh) {
      u16 hb[4];
#pragma unroll
      for (int cc = 0; cc < 4; ++cc)
        hb[cc] = to_bf16(st[lq * 16 + lh * 4 + cc][dloc]);
      *(ushort4*)(xa + rbase + lh * 4) = make_ushort4(hb[0], hb[1], hb[2], hb[3]);
    }
  }
}

// ---------------- conv via MFMA: direct-global B, single-bf16 W, 1-barrier ----------------
template <int K, int P, int OUTMODE>
__global__ __launch_bounds__(256) void k_cmf(const u16* __restrict__ xh,
                                             const u16* __restrict__ wb,
                                             const float* __restrict__ bias,
                                             u16* __restrict__ yh,
                                             float* __restrict__ eout,
                                             u16* __restrict__ ebf) {
  __shared__ float cd[3072];            // waves 1..3 partials (12 KB)

  int blk = blockIdx.x;                 // pb(3) oct(3) jt(3)
  int jt = blk & 7, oct = (blk >> 3) & 7, pb = blk >> 6;
  int oc0 = oct * 32, j0 = jt * 32;
  int tid = threadIdx.x;
  int lane = tid & 63, wv = tid >> 6;
  int l31 = lane & 31, lhi = lane >> 5;

  f32x16 acc = {};
  size_t abase = (size_t)(oc0 + l31) * 8 + (size_t)(wv * 8 + lhi) * 2048;
  const u16* brow = xh + (size_t)pb * (XROWS * 256) +
                    (size_t)(j0 + l31 + 8 - P) * 256 + wv * 64 + lhi * 8;

  for (int q = 0; q < K; ++q) {
    const u16* bsrc = brow + (size_t)q * 256;
    size_t aq = (size_t)q * 65536 + abase;
#pragma unroll
    for (int ic = 0; ic < 4; ++ic) {
      s8v ah = *(const s8v*)(wb + aq + ic * 4096);
      s8v bh = *(const s8v*)(bsrc + ic * 16);
      acc = __builtin_amdgcn_mfma_f32_32x32x16_bf16(ah, bh, acc, 0, 0, 0);
    }
  }

  if (wv > 0) {
#pragma unroll
    for (int r = 0; r < 16; ++r) {
      int ocr = (r & 3) + 8 * (r >> 2) + 4 * lhi;
      cd[(wv - 1) * 1024 + ocr * 32 + l31] = acc[r];
    }
  }
  __syncthreads();
  if (wv == 0) {
    float v[16];
#pragma unroll
    for (int r = 0; r < 16; ++r) {
      int ocr = (r & 3) + 8 * (r >> 2) + 4 * lhi;
      int idx = ocr * 32 + l31;
      v[r] = fmaxf(acc[r] + cd[idx] + cd[1024 + idx] + cd[2048 + idx] + bias[oc0 + ocr], 0.0f);
    }
    if constexpr (OUTMODE == 0) {
      size_t ro = (size_t)pb * (XROWS * 256) + (size_t)(8 + j0 + l31) * 256 + oc0 + 4 * lhi;
#pragma unroll
      for (int rq = 0; rq < 4; ++rq) {
        *(ushort4*)(yh + ro + 8 * rq) =
            make_ushort4(to_bf16(v[rq * 4 + 0]), to_bf16(v[rq * 4 + 1]),
                         to_bf16(v[rq * 4 + 2]), to_bf16(v[rq * 4 + 3]));
      }
    } else {
#pragma unroll
      for (int r = 0; r < 16; ++r) {
        int ocr = (r & 3) + 8 * (r >> 2) + 4 * lhi;
        size_t eo = (size_t)pb * 65536 + (size_t)(oc0 + ocr) * 256 + j0 + l31;
        eout[eo] = v[r];
        ebf[((size_t)pb * 256 + oc0 + ocr) * 256 + j0 + l31] = to_bf16(v[r]);
      }
    }
  }
}

// ---------------- fused jam (512 blocks) + scores (256 blocks, spin-chained) ----------
__global__ __launch_bounds__(256) void k_js(const u16* __restrict__ ebf,
                                            const u16* __restrict__ wj,
                                            const float* __restrict__ b1,
                                            const float* __restrict__ b2,
                                            u16* __restrict__ qk,
                                            float* __restrict__ S,
                                            float* __restrict__ bsums,
                                            int* __restrict__ cnt) {
  __shared__ float cd[4128];
  int bid = blockIdx.x;
  int tid = threadIdx.x, wv = tid >> 6, lane = tid & 63;
  int l31 = lane & 31, lhi = lane >> 5;

  if (bid < 512) {
    // ---- jam: q/k projection ----
    int blk = bid;                      // pb(3) it(3) nt(3)
    int nt = blk & 7, it = (blk >> 3) & 7, pb = blk >> 6;
    int p = pb >> 2;
    int i0 = it * 32, n0 = nt * 32;

    const u16* eh = ebf + ((size_t)pb * 256 + i0 + l31) * 256 + lhi * 8;
    const u16* wjh = wj + (size_t)(p * 2) * 65536;

    f32x16 acc = {};
#pragma unroll
    for (int c = 0; c < 4; ++c) {
      int kc = wv * 4 + c;
      int kg = kc * 2 + lhi;
      s8v ah = *(const s8v*)(eh + kc * 16);
      s8v bh = *(const s8v*)(wjh + ((size_t)kg * 256 + n0 + l31) * 8);
      s8v bl = *(const s8v*)(wjh + 65536 + ((size_t)kg * 256 + n0 + l31) * 8);
      acc = __builtin_amdgcn_mfma_f32_32x32x16_bf16(ah, bh, acc, 0, 0, 0);
      acc = __builtin_amdgcn_mfma_f32_32x32x16_bf16(ah, bl, acc, 0, 0, 0);
    }

    if (wv > 0) {
#pragma unroll
      for (int r = 0; r < 16; ++r) {
        int row = (r & 3) + 8 * (r >> 2) + 4 * lhi;
        cd[(wv - 1) * 1024 + row * 32 + l31] = acc[r];
      }
    }
    __syncthreads();
    if (wv == 0) {
      float bv = (p ? b2 : b1)[n0 + l31];
#pragma unroll
      for (int r = 0; r < 16; ++r) {
        int row = (r & 3) + 8 * (r >> 2) + 4 * lhi;
        int idx = row * 32 + l31;
        cd[3072 + row * 33 + l31] = acc[r] + cd[idx] + cd[1024 + idx] + cd[2048 + idx] + bv;
      }
    }
    __syncthreads();

    int row = tid & 31, c8 = tid >> 5;
    u16 hb[4];
#pragma unroll
    for (int cc = 0; cc < 4; ++cc)
      hb[cc] = to_bf16(cd[3072 + row * 33 + c8 * 4 + cc]);
    size_t ro = ((size_t)pb * 256 + i0 + row) * 256 + n0 + c8 * 4;
    *(ushort4*)(qk + ro) = make_ushort4(hb[0], hb[1], hb[2], hb[3]);
    signal_done(&cnt[0]);
  } else {
    // ---- scores: wait for all q/k then sigmoid(q k^T) ----
    spin_until(&cnt[0], 512);
    int blk = bid - 512;                // b(2) it(3) jt(3)
    int jt = blk & 7, it = (blk >> 3) & 7, b = blk >> 6;
    int i0 = it * 32, j0 = jt * 32;

    const u16* qh = qk + ((size_t)b * 256 + i0 + l31) * 256 + lhi * 8;
    const u16* kh = qk + ((size_t)(4 + b) * 256 + j0 + l31) * 256 + lhi * 8;

    f32x16 acc = {};
#pragma unroll
    for (int c = 0; c < 4; ++c) {
      int kc = wv * 4 + c;
      s8v a = *(const s8v*)(qh + kc * 16);
      s8v bb = *(const s8v*)(kh + kc * 16);
      acc = __builtin_amdgcn_mfma_f32_32x32x16_bf16(a, bb, acc, 0, 0, 0);
    }

    if (wv > 0) {
#pragma unroll
      for (int r = 0; r < 16; ++r) {
        int row = (r & 3) + 8 * (r >> 2) + 4 * lhi;
        cd[(wv - 1) * 1024 + row * 32 + l31] = acc[r];
      }
    }
    __syncthreads();
    if (wv == 0) {
      float psum = 0.0f;
#pragma unroll
      for (int r = 0; r < 16; ++r) {
        int row = (r & 3) + 8 * (r >> 2) + 4 * lhi;
        int idx = row * 32 + l31;
        float s = sig_fast(acc[r] + cd[idx] + cd[1024 + idx] + cd[2048 + idx]);
        psum += s;
        cd[3072 + row * 33 + l31] = s;
      }
      for (int off = 32; off; off >>= 1) psum += __shfl_down(psum, off, 64);
      if (lane == 0) bsums[blk] = psum;
    }
    __syncthreads();

    int row = tid & 31, c8 = tid >> 5;
    float4 v;
    v.x = cd[3072 + row * 33 + c8 * 4 + 0];
    v.y = cd[3072 + row * 33 + c8 * 4 + 1];
    v.z = cd[3072 + row * 33 + c8 * 4 + 2];
    v.w = cd[3072 + row * 33 + c8 * 4 + 3];
    *(float4*)(S + ((size_t)b * 256 + i0 + row) * 256 + j0 + c8 * 4) = v;
  }
}

// ---------------- fused tail: pool -> poolcomb -> fc1(+head) -> fc2 -> fc3 ------------
__global__ __launch_bounds__(256) void k_tail(const float* __restrict__ e1,
                                              const float* __restrict__ e2,
                                              const float* __restrict__ S,
                                              const float* __restrict__ bsums,
                                              float* __restrict__ inter_out,
                                              float* __restrict__ pp,
                                              float* __restrict__ pooled,
                                              const float* __restrict__ rcw,
                                              const float* __restrict__ rcb,
                                              const float* __restrict__ fc1w,
                                              float* __restrict__ f1p,
                                              const float* __restrict__ fc1b,
                                              const float* __restrict__ fc2w,
                                              const float* __restrict__ fc2b,
                                              const float* __restrict__ fc3w,
                                              const float* __restrict__ fc3b,
                                              float* __restrict__ h2g,
                                              float* __restrict__ out,
                                              int* __restrict__ cnt) {
  __shared__ float sm[2408];
  int bid = blockIdx.x;
  int t = threadIdx.x;

  if (bid < 2048) {
    // ---- pool producer: one 8i x 16k tile ----
    int blk = bid;                      // b(2) ich(5) kch(4)
    int kch = blk & 15, ich = (blk >> 4) & 31, b = blk >> 9;
    int d = t, i0 = ich * 8, k0 = kch * 16;
    float* s2 = sm;                     // [kk*8+ii], 128
    float* red = sm + 128;              // 128
    int ii = t >> 4, kk = t & 15;
    float sv = 0.0f;
    if (t < 64) {
      float v = bsums[b * 64 + t];
      for (int off = 32; off; off >>= 1) v += __shfl_down(v, off, 64);
      if (t == 0) sm[257] = v;          // tot
    }
    if (t < 128) {
      sv = S[((size_t)(b * 256 + i0 + ii)) * 256 + k0 + kk];
      s2[kk * 8 + ii] = 2.0f * sv;
      red[t] = sv;
    }
    __syncthreads();
    for (int st = 64; st; st >>= 1) {
      if (t < st) red[t] += red[t + st];
      __syncthreads();
    }
    if (t == 0) sm[256] = red[0];       // ssp
    __syncthreads();

    float invt = 1.0f / sm[257];
    float ssp = sm[256];
    if (t < 128)
      inter_out[((size_t)(b * 256 + i0 + ii)) * 256 + k0 + kk] = sv * invt;

    constexpr float C2L = 2.8853900817779268f;   // 2*log2(e)
    float ev2[8];
#pragma unroll
    for (int i2 = 0; i2 < 8; ++i2)
      ev2[i2] = e1[((size_t)(b * L + i0 + i2)) * D + d] * C2L;

    float a0 = 0.f, a1 = 0.f, a2 = 0.f, a3 = 0.f;
    for (int k2 = 0; k2 < 16; ++k2) {
      float e2v = e2[((size_t)(b * L + k0 + k2)) * D + d];
      float s2r[8];
      *(float4*)&s2r[0] = *(const float4*)&s2[k2 * 8];
      *(float4*)&s2r[4] = *(const float4*)&s2[k2 * 8 + 4];
#pragma unroll
      for (int i2 = 0; i2 < 8; ++i2) {
        float r = __builtin_amdgcn_rcpf(__builtin_exp2f(ev2[i2] * e2v) + 1.0f);
        if ((i2 & 3) == 0) a0 = fmaf(r, s2r[i2], a0);
        else if ((i2 & 3) == 1) a1 = fmaf(r, s2r[i2], a1);
        else if ((i2 & 3) == 2) a2 = fmaf(r, s2r[i2], a2);
        else a3 = fmaf(r, s2r[i2], a3);
      }
    }
    float res = (ssp - (a0 + a1 + a2 + a3)) * invt;
    pp[(((size_t)b * 32 + ich) * 16 + kch) * 256 + d] = res;
    signal_done(&cnt[1]);
  } else if (bid < 2080) {
    // ---- poolcomb ----
    spin_until(&cnt[1], 2048);
    int s = bid - 2048;                 // b(2) dt(3)
    int dt = s & 7, b = s >> 3;
    int dl = t & 31, mg = t >> 5;
    int d = dt * 32 + dl;
    float acc = 0.f;
#pragma unroll
    for (int m = 0; m < 64; ++m)
      acc += pp[((size_t)b * 512 + mg * 64 + m) * 256 + d];
    sm[mg * 32 + dl] = acc;
    __syncthreads();
    if (mg == 0) {
      float tot = sm[dl] + sm[32 + dl] + sm[64 + dl] + sm[96 + dl] +
                  sm[128 + dl] + sm[160 + dl] + sm[192 + dl] + sm[224 + dl];
      pooled[b * 256 + d] = tot;
    }
    signal_done(&cnt[2]);
  } else if (bid < 2400) {
    // ---- fc1 with fused head conv+maxpool ----
    spin_until(&cnt[2], 32);
    int s = bid - 2080;
    int ich = s & 31, ot = s >> 5;
    float* spb = sm;                    // [4][258] = 1032
    float* hs = sm + 1032;              // [4][64]
#pragma unroll
    for (int ss = 0; ss < 4; ++ss) {
      int idx = ss * 256 + t;
      spb[(idx >> 8) * 258 + (idx & 255) + 1] = pooled[idx];
    }
    if (t < 4) { spb[t * 258] = 0.0f; spb[t * 258 + 257] = 0.0f; }
    __syncthreads();
    {
      int b = t >> 6, idx = t & 63;
      int c = ich * 2 + (idx >> 5), m = idx & 31;
      float w0 = rcw[c * 4 + 0], w1 = rcw[c * 4 + 1], w2 = rcw[c * 4 + 2], w3 = rcw[c * 4 + 3];
      float bias = rcb[c];
      float mx = -1e30f;
#pragma unroll
      for (int r = 0; r < 4; ++r) {
        int p2 = 2 * (4 * m + r);
        float y = bias;
        y = fmaf(w0, spb[b * 258 + p2], y);
        y = fmaf(w1, spb[b * 258 + p2 + 1], y);
        y = fmaf(w2, spb[b * 258 + p2 + 2], y);
        y = fmaf(w3, spb[b * 258 + p2 + 3], y);
        mx = fmaxf(mx, lrelu(y));
      }
      hs[b * 64 + idx] = mx;
    }
    __syncthreads();

    int ol = t & 63, b = t >> 6;
    int o = ot * 64 + ol;
    int oc_ = o < 600 ? o : 599;
    const float* wbp = fc1w + (size_t)(ich * 64) * 600 + oc_;
    float a0 = 0.f, a1 = 0.f, a2 = 0.f, a3 = 0.f;
#pragma unroll 4
    for (int i = 0; i < 64; i += 4) {
      a0 = fmaf(hs[b * 64 + i], wbp[(size_t)i * 600], a0);
      a1 = fmaf(hs[b * 64 + i + 1], wbp[(size_t)(i + 1) * 600], a1);
      a2 = fmaf(hs[b * 64 + i + 2], wbp[(size_t)(i + 2) * 600], a2);
      a3 = fmaf(hs[b * 64 + i + 3], wbp[(size_t)(i + 3) * 600], a3);
    }
    if (o < 600) f1p[((size_t)ich * 4 + b) * 600 + o] = a0 + a1 + a2 + a3;
    signal_done(&cnt[3]);
  } else if (bid < 2405) {
    // ---- fc2 (full-i): h1 combine in LDS, write h2 ----
    spin_until(&cnt[3], 320);
    int ot = bid - 2400;
    for (int e = t; e < 2400; e += 256) {
      int bb = e / 600, ii = e % 600;
      float s = fc1b[ii];
#pragma unroll
      for (int ich = 0; ich < 32; ++ich) s += f1p[((size_t)ich * 4 + bb) * 600 + ii];
      sm[bb * 601 + ii] = lrelu(s);
    }
    __syncthreads();
    int ol = t & 63, b = t >> 6;
    int o = ot * 64 + ol;
    if (o < 300) {
      const float* wbp = fc2w + o;
      float a0 = 0.f, a1 = 0.f, a2 = 0.f, a3 = 0.f;
#pragma unroll 2
      for (int ii = 0; ii < 600; ii += 4) {
        a0 = fmaf(sm[b * 601 + ii], wbp[(size_t)ii * 300], a0);
        a1 = fmaf(sm[b * 601 + ii + 1], wbp[(size_t)(ii + 1) * 300], a1);
        a2 = fmaf(sm[b * 601 + ii + 2], wbp[(size_t)(ii + 2) * 300], a2);
        a3 = fmaf(sm[b * 601 + ii + 3], wbp[(size_t)(ii + 3) * 300], a3);
      }
      h2g[b * 300 + o] = lrelu(fc2b[o] + a0 + a1 + a2 + a3);
    }
    signal_done(&cnt[4]);
  } else {
    // ---- fc3 ----
    spin_until(&cnt[4], 5);
    for (int e = t; e < 1200; e += 256) {
      int b = e / 300, o = e % 300;
      sm[b * 301 + o] = h2g[b * 300 + o];
    }
    __syncthreads();
    int wv = t >> 6, l = t & 63;
    if (wv < 4) {
      float s = 0.f;
#pragma unroll
      for (int m = 0; m < 5; ++m) {
        int i = m * 64 + l;
        if (i < 300) s = fmaf(sm[wv * 301 + i], fc3w[i], s);
      }
      for (int off = 32; off; off >>= 1) s += __shfl_down(s, off, 64);
      if (l == 0) out[262144 + wv] = s + fc3b[0];
    }
  }
}

extern "C" void kernel_launch(void* const* d_in, const int* in_sizes, int n_in,
                              void* d_out, int out_size, void* d_ws, size_t ws_size,
                              hipStream_t stream) {
  float* ws = (float*)d_ws;
  const int* p1 = (const int*)d_in[0];
  const int* p2 = (const int*)d_in[1];
  const float* emb  = (const float*)d_in[2];
  const float* w0   = (const float*)d_in[3];
  const float* b0   = (const float*)d_in[4];
  const float* w1   = (const float*)d_in[5];
  const float* b1   = (const float*)d_in[6];
  const float* w2   = (const float*)d_in[7];
  const float* b2   = (const float*)d_in[8];
  const float* ja1w = (const float*)d_in[9];
  const float* ja1b = (const float*)d_in[10];
  const float* ja2w = (const float*)d_in[11];
  const float* ja2b = (const float*)d_in[12];
  const float* rcw  = (const float*)d_in[13];
  const float* rcb  = (const float*)d_in[14];
  const float* fc1w = (const float*)d_in[15];
  const float* fc1b = (const float*)d_in[16];
  const float* fc2w = (const float*)d_in[17];
  const float* fc2b = (const float*)d_in[18];
  const float* fc3w = (const float*)d_in[19];
  const float* fc3b = (const float*)d_in[20];
  float* out = (float*)d_out;

  u16* xa  = (u16*)(ws + OFF_XA);
  u16* xb  = (u16*)(ws + OFF_XB);
  u16* wbu = (u16*)(ws + OFF_WB);
  u16* wju = (u16*)(ws + OFF_WJ);
  u16* ebf = (u16*)(ws + OFF_EBF);
  u16* qk  = (u16*)(ws + OFF_QK);
  int* cnt = (int*)(ws + OFF_CNT);

  k_prepall<<<1024, 256, 0, stream>>>(p1, p2, emb, w0, w1, w2, ja1w, ja2w, xa, xb, wbu, wju,
                                      cnt);

  k_cmf<4, 1, 0><<<512, 256, 0, stream>>>(xa, wbu + WB_L1, b0, xb, nullptr, nullptr);
  k_cmf<8, 3, 0><<<512, 256, 0, stream>>>(xb, wbu + WB_L2, b1, xa, nullptr, nullptr);
  k_cmf<12, 5, 1><<<512, 256, 0, stream>>>(xa, wbu + WB_L3, b2, nullptr, ws + OFF_E, ebf);

  k_js<<<768, 256, 0, stream>>>(ebf, wju, ja1b, ja2b, qk, ws + OFF_S, ws + OFF_BS, cnt);

  k_tail<<<2406, 256, 0, stream>>>(ws + OFF_E, ws + OFF_E + SZ, ws + OFF_S, ws + OFF_BS,
                                   out, ws + OFF_PP, ws + OFF_POOL, rcw, rcb,
                                   fc1w, ws + OFF_F1P, fc1b, fc2w, fc2b, fc3w, fc3b,
                                   ws + OFF_H2, out, cnt);
}

// Round 13
// 96.032 us; speedup vs baseline: 5.0210x; 2.7379x over previous
//
#include <hip/hip_runtime.h>
#include <hip/hip_bf16.h>

typedef unsigned short u16;
typedef unsigned int u32;
typedef short s8v __attribute__((ext_vector_type(8)));      // 8 bf16 bit-patterns
typedef float f32x16 __attribute__((ext_vector_type(16)));

constexpr int B = 4, L = 256, D = 256;
constexpr size_t SZ = (size_t)B * L * D;          // 262144

// Xt (transposed, padded): rows = spatial(-8..263) -> 272, cols = channel 0..255
constexpr int XROWS = 272;

// workspace offsets (floats)
constexpr size_t OFF_E    = 0;                        // 2*SZ fp32 e
constexpr size_t OFF_S    = 2 * SZ;                   // 262144 (raw sigmoid)
constexpr size_t OFF_EBF  = 3 * SZ;                   // 262144 (bf16 plane, 8 pb)
constexpr size_t OFF_XA   = 4 * SZ;                   // 278528
constexpr size_t OFF_XB   = OFF_XA + 278528;          // 278528
constexpr size_t OFF_WB   = OFF_XB + 278528;          // 786432 (single-plane conv W)
constexpr size_t OFF_WJ   = OFF_WB + 786432;          // 131072 (hi/lo ja weights)
constexpr size_t OFF_QK   = OFF_WJ + 131072;          // 262144
constexpr size_t OFF_BS   = OFF_QK + 262144;          // 256
constexpr size_t OFF_PP   = OFF_BS + 256;             // 524288
constexpr size_t OFF_POOL = OFF_PP + 524288;          // 1024
constexpr size_t OFF_F1P  = OFF_POOL + 1024;          // 76800
constexpr size_t OFF_F2P  = OFF_F1P + 76800;          // 9600

// Wb layer offsets in ushorts (single plane: K q-planes of 65536)
constexpr size_t WB_L1 = 0;
constexpr size_t WB_L2 = (size_t)4 * 65536;           // 262144
constexpr size_t WB_L3 = (size_t)12 * 65536;          // 786432

__device__ __forceinline__ float sig_fast(float x) {
  return __fdividef(1.0f, 1.0f + __expf(-x));
}
__device__ __forceinline__ float lrelu(float x) { return x >= 0.0f ? x : 0.1f * x; }

__device__ __forceinline__ void split_bf16(float v, u16& h, u16& l) {
  __bf16 hb = (__bf16)v;
  float hf = (float)hb;
  __bf16 lb = (__bf16)(v - hf);
  h = __builtin_bit_cast(u16, hb);
  l = __builtin_bit_cast(u16, lb);
}
__device__ __forceinline__ u16 to_bf16(float v) {
  return __builtin_bit_cast(u16, (__bf16)v);
}

// ---------------- fused prep: pad-zero + weight prep + embed/transpose ----------------
__global__ __launch_bounds__(256) void k_prepall(const int* __restrict__ t1,
                                                 const int* __restrict__ t2,
                                                 const float* __restrict__ emb,
                                                 const float* __restrict__ w0,
                                                 const float* __restrict__ w1,
                                                 const float* __restrict__ w2,
                                                 const float* __restrict__ jw1,
                                                 const float* __restrict__ jw2,
                                                 u16* __restrict__ xa,
                                                 u16* __restrict__ xb,
                                                 u16* __restrict__ wb,
                                                 u16* __restrict__ wj) {
  __shared__ float st[32][129];
  int blk = blockIdx.x;
  int t = threadIdx.x;
  if (blk < 64) {
    int gid = blk * 256 + t;                    // 0..16383
    int plane = gid >> 13, rem = gid & 8191;
    int pb = rem >> 10, rem2 = rem & 1023;
    int row16 = rem2 >> 6, cc = rem2 & 63;
    int row = row16 < 8 ? row16 : 256 + row16;
    u16* dst = plane ? xb : xa;
    *(ushort4*)(dst + (size_t)pb * (XROWS * 256) + (size_t)row * 256 + cc * 4) =
        make_ushort4(0, 0, 0, 0);
  } else if (blk < 896) {
    int b2 = blk - 64;                          // 0..831
    if (b2 < 768) {
      const float* w; u16* dst; int K, lblk;
      if (b2 < 128) { w = w0; dst = wb + WB_L1; K = 4; lblk = b2; }
      else if (b2 < 384) { w = w1; dst = wb + WB_L2; K = 8; lblk = b2 - 128; }
      else { w = w2; dst = wb + WB_L3; K = 12; lblk = b2 - 384; }
      int q = lblk >> 5, ig = lblk & 31, oc = t;
      union { u16 us[8]; uint4 v; } H;
#pragma unroll
      for (int e = 0; e < 8; ++e)
        H.us[e] = to_bf16(w[((size_t)oc * 256 + ig * 8 + e) * K + q]);
      *(uint4*)(dst + (size_t)q * 65536 + (size_t)ig * 2048 + (size_t)oc * 8) = H.v;
    } else {
      int lblk = b2 - 768;
      int kg = lblk & 31, p = lblk >> 5;
      const float* W = p ? jw2 : jw1;
      int n = t;
      union { u16 us[8]; uint4 v; } H, Lo;
#pragma unroll
      for (int e = 0; e < 8; ++e) {
        float v = W[(size_t)(kg * 8 + e) * 256 + n];
        split_bf16(v, H.us[e], Lo.us[e]);
      }
      size_t d = (size_t)(p * 2) * 65536 + ((size_t)kg * 256 + n) * 8;
      *(uint4*)(wj + d) = H.v;
      *(uint4*)(wj + d + 65536) = Lo.v;
    }
  } else {
    // embedding + transpose -> xa (single bf16 plane)
    int lb = blk - 896;                         // pb(3) lt(3) dt(1)
    int dt = lb & 1, lt = (lb >> 1) & 7, pb = lb >> 4;
    int l0 = lt * 32, d0 = dt * 128;
    const int* tok = (pb >> 2) ? t2 : t1;
    int c = t & 127, rq = t >> 7;
#pragma unroll 4
    for (int rr = 0; rr < 16; ++rr) {
      int r = rr * 2 + rq;
      int tv = tok[(pb & 3) * 256 + l0 + r];
      st[r][c] = emb[(size_t)tv * 256 + d0 + c];
    }
    __syncthreads();
    int dloc = t >> 1, lq = t & 1;
    size_t rbase = (size_t)pb * (XROWS * 256) + (size_t)(8 + d0 + dloc) * 256 + l0 + lq * 16;
#pragma unroll
    for (int lh = 0; lh < 4; ++lh) {
      u16 hb[4];
#pragma unroll
      for (int cc = 0; cc < 4; ++cc)
        hb[cc] = to_bf16(st[lq * 16 + lh * 4 + cc][dloc]);
      *(ushort4*)(xa + rbase + lh * 4) = make_ushort4(hb[0], hb[1], hb[2], hb[3]);
    }
  }
}

// ---------------- conv via MFMA: direct-global B, single-bf16 W, 1-barrier ----------------
template <int K, int P, int OUTMODE>
__global__ __launch_bounds__(256) void k_cmf(const u16* __restrict__ xh,
                                             const u16* __restrict__ wb,
                                             const float* __restrict__ bias,
                                             u16* __restrict__ yh,
                                             float* __restrict__ eout,
                                             u16* __restrict__ ebf) {
  __shared__ float cd[3072];            // waves 1..3 partials (12 KB)

  int blk = blockIdx.x;                 // pb(3) oct(3) jt(3)
  int jt = blk & 7, oct = (blk >> 3) & 7, pb = blk >> 6;
  int oc0 = oct * 32, j0 = jt * 32;
  int tid = threadIdx.x;
  int lane = tid & 63, wv = tid >> 6;
  int l31 = lane & 31, lhi = lane >> 5;

  f32x16 acc = {};
  size_t abase = (size_t)(oc0 + l31) * 8 + (size_t)(wv * 8 + lhi) * 2048;
  const u16* brow = xh + (size_t)pb * (XROWS * 256) +
                    (size_t)(j0 + l31 + 8 - P) * 256 + wv * 64 + lhi * 8;

  for (int q = 0; q < K; ++q) {
    const u16* bsrc = brow + (size_t)q * 256;
    size_t aq = (size_t)q * 65536 + abase;
#pragma unroll
    for (int ic = 0; ic < 4; ++ic) {
      s8v ah = *(const s8v*)(wb + aq + ic * 4096);
      s8v bh = *(const s8v*)(bsrc + ic * 16);
      acc = __builtin_amdgcn_mfma_f32_32x32x16_bf16(ah, bh, acc, 0, 0, 0);
    }
  }

  if (wv > 0) {
#pragma unroll
    for (int r = 0; r < 16; ++r) {
      int ocr = (r & 3) + 8 * (r >> 2) + 4 * lhi;
      cd[(wv - 1) * 1024 + ocr * 32 + l31] = acc[r];
    }
  }
  __syncthreads();
  if (wv == 0) {
    float v[16];
#pragma unroll
    for (int r = 0; r < 16; ++r) {
      int ocr = (r & 3) + 8 * (r >> 2) + 4 * lhi;
      int idx = ocr * 32 + l31;
      v[r] = fmaxf(acc[r] + cd[idx] + cd[1024 + idx] + cd[2048 + idx] + bias[oc0 + ocr], 0.0f);
    }
    if constexpr (OUTMODE == 0) {
      size_t ro = (size_t)pb * (XROWS * 256) + (size_t)(8 + j0 + l31) * 256 + oc0 + 4 * lhi;
#pragma unroll
      for (int rq = 0; rq < 4; ++rq) {
        *(ushort4*)(yh + ro + 8 * rq) =
            make_ushort4(to_bf16(v[rq * 4 + 0]), to_bf16(v[rq * 4 + 1]),
                         to_bf16(v[rq * 4 + 2]), to_bf16(v[rq * 4 + 3]));
      }
    } else {
#pragma unroll
      for (int r = 0; r < 16; ++r) {
        int ocr = (r & 3) + 8 * (r >> 2) + 4 * lhi;
        size_t eo = (size_t)pb * 65536 + (size_t)(oc0 + ocr) * 256 + j0 + l31;
        eout[eo] = v[r];
        ebf[((size_t)pb * 256 + oc0 + ocr) * 256 + j0 + l31] = to_bf16(v[r]);
      }
    }
  }
}

// ---------------- ja projections: e (bf16) x W (hi/lo) -> 2 MFMAs, q/k bf16 ----------------
__global__ __launch_bounds__(256) void k_jam(const u16* __restrict__ ebf,
                                             const u16* __restrict__ wj,
                                             const float* __restrict__ b1,
                                             const float* __restrict__ b2,
                                             u16* __restrict__ qk) {
  __shared__ float cd[3072 + 1056];
  int blk = blockIdx.x;                 // pb(3) it(3) nt(3)
  int nt = blk & 7, it = (blk >> 3) & 7, pb = blk >> 6;
  int p = pb >> 2;
  int i0 = it * 32, n0 = nt * 32;
  int tid = threadIdx.x, wv = tid >> 6, lane = tid & 63;
  int l31 = lane & 31, lhi = lane >> 5;

  const u16* eh = ebf + ((size_t)pb * 256 + i0 + l31) * 256 + lhi * 8;
  const u16* wjh = wj + (size_t)(p * 2) * 65536;

  f32x16 acc = {};
#pragma unroll
  for (int c = 0; c < 4; ++c) {
    int kc = wv * 4 + c;
    int kg = kc * 2 + lhi;
    s8v ah = *(const s8v*)(eh + kc * 16);
    s8v bh = *(const s8v*)(wjh + ((size_t)kg * 256 + n0 + l31) * 8);
    s8v bl = *(const s8v*)(wjh + 65536 + ((size_t)kg * 256 + n0 + l31) * 8);
    acc = __builtin_amdgcn_mfma_f32_32x32x16_bf16(ah, bh, acc, 0, 0, 0);
    acc = __builtin_amdgcn_mfma_f32_32x32x16_bf16(ah, bl, acc, 0, 0, 0);
  }

  if (wv > 0) {
#pragma unroll
    for (int r = 0; r < 16; ++r) {
      int row = (r & 3) + 8 * (r >> 2) + 4 * lhi;
      cd[(wv - 1) * 1024 + row * 32 + l31] = acc[r];
    }
  }
  __syncthreads();
  if (wv == 0) {
    float bv = (p ? b2 : b1)[n0 + l31];
#pragma unroll
    for (int r = 0; r < 16; ++r) {
      int row = (r & 3) + 8 * (r >> 2) + 4 * lhi;
      int idx = row * 32 + l31;
      cd[3072 + row * 33 + l31] = acc[r] + cd[idx] + cd[1024 + idx] + cd[2048 + idx] + bv;
    }
  }
  __syncthreads();

  int row = tid & 31, c8 = tid >> 5;
  u16 hb[4];
#pragma unroll
  for (int cc = 0; cc < 4; ++cc)
    hb[cc] = to_bf16(cd[3072 + row * 33 + c8 * 4 + cc]);
  size_t ro = ((size_t)pb * 256 + i0 + row) * 256 + n0 + c8 * 4;
  *(ushort4*)(qk + ro) = make_ushort4(hb[0], hb[1], hb[2], hb[3]);
}

// ---------------- scores: q x k (both bf16) -> 1 MFMA per chunk ----------------
__global__ __launch_bounds__(256) void k_scoresm(const u16* __restrict__ qk,
                                                 float* __restrict__ S,
                                                 float* __restrict__ bsums) {
  __shared__ float cd[3072 + 1056];
  int blk = blockIdx.x;                 // b(2) it(3) jt(3)
  int jt = blk & 7, it = (blk >> 3) & 7, b = blk >> 6;
  int i0 = it * 32, j0 = jt * 32;
  int tid = threadIdx.x, wv = tid >> 6, lane = tid & 63;
  int l31 = lane & 31, lhi = lane >> 5;

  const u16* qh = qk + ((size_t)b * 256 + i0 + l31) * 256 + lhi * 8;
  const u16* kh = qk + ((size_t)(4 + b) * 256 + j0 + l31) * 256 + lhi * 8;

  f32x16 acc = {};
#pragma unroll
  for (int c = 0; c < 4; ++c) {
    int kc = wv * 4 + c;
    s8v a = *(const s8v*)(qh + kc * 16);
    s8v bb = *(const s8v*)(kh + kc * 16);
    acc = __builtin_amdgcn_mfma_f32_32x32x16_bf16(a, bb, acc, 0, 0, 0);
  }

  if (wv > 0) {
#pragma unroll
    for (int r = 0; r < 16; ++r) {
      int row = (r & 3) + 8 * (r >> 2) + 4 * lhi;
      cd[(wv - 1) * 1024 + row * 32 + l31] = acc[r];
    }
  }
  __syncthreads();
  if (wv == 0) {
    float psum = 0.0f;
#pragma unroll
    for (int r = 0; r < 16; ++r) {
      int row = (r & 3) + 8 * (r >> 2) + 4 * lhi;
      int idx = row * 32 + l31;
      float s = sig_fast(acc[r] + cd[idx] + cd[1024 + idx] + cd[2048 + idx]);
      psum += s;
      cd[3072 + row * 33 + l31] = s;
    }
    for (int off = 32; off; off >>= 1) psum += __shfl_down(psum, off, 64);
    if (lane == 0) bsums[blk] = psum;
  }
  __syncthreads();

  int row = tid & 31, c8 = tid >> 5;
  float4 v;
  v.x = cd[3072 + row * 33 + c8 * 4 + 0];
  v.y = cd[3072 + row * 33 + c8 * 4 + 1];
  v.z = cd[3072 + row * 33 + c8 * 4 + 2];
  v.w = cd[3072 + row * 33 + c8 * 4 + 3];
  *(float4*)(S + ((size_t)b * 256 + i0 + row) * 256 + j0 + c8 * 4) = v;
}

// ---------------- bilinear tanh pooling from raw S (+ writes normalized inter) --------
__global__ __launch_bounds__(256) void k_pool(const float* __restrict__ e1,
                                              const float* __restrict__ e2,
                                              const float* __restrict__ S,
                                              const float* __restrict__ bsums,
                                              float* __restrict__ inter_out,
                                              float* __restrict__ pp) {
  int blk = blockIdx.x;                 // b(2) ich(5) kch(4)
  int kch = blk & 15, ich = (blk >> 4) & 31, b = blk >> 9;
  int d = threadIdx.x, i0 = ich * 8, k0 = kch * 16;
  __shared__ float s2[16][8];
  __shared__ float red[128];
  __shared__ float ssp_s, tot_s;
  int t = threadIdx.x;
  int ii = t >> 4, kk = t & 15;
  float sv = 0.0f;
  if (t < 64) {
    float v = bsums[b * 64 + t];
    for (int off = 32; off; off >>= 1) v += __shfl_down(v, off, 64);
    if (t == 0) tot_s = v;
  }
  if (t < 128) {
    sv = S[((size_t)(b * 256 + i0 + ii)) * 256 + k0 + kk];
    s2[kk][ii] = 2.0f * sv;
    red[t] = sv;
  }
  __syncthreads();
  for (int st = 64; st; st >>= 1) {
    if (t < st) red[t] += red[t + st];
    __syncthreads();
  }
  if (t == 0) ssp_s = red[0];
  __syncthreads();

  float invt = 1.0f / tot_s;
  if (t < 128)
    inter_out[((size_t)(b * 256 + i0 + ii)) * 256 + k0 + kk] = sv * invt;

  constexpr float C2L = 2.8853900817779268f;   // 2*log2(e)
  float ev2[8];
#pragma unroll
  for (int i2 = 0; i2 < 8; ++i2)
    ev2[i2] = e1[((size_t)(b * L + i0 + i2)) * D + d] * C2L;

  float a0 = 0.f, a1 = 0.f, a2 = 0.f, a3 = 0.f;
  for (int k2 = 0; k2 < 16; ++k2) {
    float e2v = e2[((size_t)(b * L + k0 + k2)) * D + d];
    float s2r[8];
    *(float4*)&s2r[0] = *(const float4*)&s2[k2][0];
    *(float4*)&s2r[4] = *(const float4*)&s2[k2][4];
#pragma unroll
    for (int i2 = 0; i2 < 8; ++i2) {
      float r = __builtin_amdgcn_rcpf(__builtin_exp2f(ev2[i2] * e2v) + 1.0f);
      if ((i2 & 3) == 0) a0 = fmaf(r, s2r[i2], a0);
      else if ((i2 & 3) == 1) a1 = fmaf(r, s2r[i2], a1);
      else if ((i2 & 3) == 2) a2 = fmaf(r, s2r[i2], a2);
      else a3 = fmaf(r, s2r[i2], a3);
    }
  }
  float res = (ssp_s - (a0 + a1 + a2 + a3)) * invt;
  pp[(((size_t)b * 32 + ich) * 16 + kch) * 256 + d] = res;
}

__global__ __launch_bounds__(256) void k_poolcomb(const float* __restrict__ pp,
                                                  float* __restrict__ pooled) {
  int blk = blockIdx.x;                 // b(2) dt(3)
  int dt = blk & 7, b = blk >> 3;
  int t = threadIdx.x, dl = t & 31, mg = t >> 5;
  int d = dt * 32 + dl;
  float s = 0.f;
#pragma unroll
  for (int m = 0; m < 64; ++m)
    s += pp[((size_t)b * 512 + mg * 64 + m) * 256 + d];
  __shared__ float red[8][32];
  red[mg][dl] = s;
  __syncthreads();
  if (mg == 0) {
    float tot = red[0][dl] + red[1][dl] + red[2][dl] + red[3][dl] +
                red[4][dl] + red[5][dl] + red[6][dl] + red[7][dl];
    pooled[b * 256 + d] = tot;
  }
}

// ---------------- fc1 with fused head (conv+pool from pooled) ----------------
__global__ __launch_bounds__(256) void k_fc1h(const float* __restrict__ pooled,
                                              const float* __restrict__ rcw,
                                              const float* __restrict__ rcb,
                                              const float* __restrict__ w,
                                              float* __restrict__ f1p) {
  int blk = blockIdx.x;
  int ich = blk & 31, ot = blk >> 5;
  __shared__ float spb[4][258];
  __shared__ float hs[4][64];
  int t = threadIdx.x;
#pragma unroll
  for (int s = 0; s < 4; ++s) {
    int idx = s * 256 + t;
    spb[idx >> 8][(idx & 255) + 1] = pooled[idx];
  }
  if (t < 4) { spb[t][0] = 0.0f; spb[t][257] = 0.0f; }
  __syncthreads();
  {
    int b = t >> 6, idx = t & 63;
    int c = ich * 2 + (idx >> 5), m = idx & 31;
    float w0 = rcw[c * 4 + 0], w1 = rcw[c * 4 + 1], w2 = rcw[c * 4 + 2], w3 = rcw[c * 4 + 3];
    float bias = rcb[c];
    float mx = -1e30f;
#pragma unroll
    for (int r = 0; r < 4; ++r) {
      int p2 = 2 * (4 * m + r);
      float y = bias;
      y = fmaf(w0, spb[b][p2], y);
      y = fmaf(w1, spb[b][p2 + 1], y);
      y = fmaf(w2, spb[b][p2 + 2], y);
      y = fmaf(w3, spb[b][p2 + 3], y);
      mx = fmaxf(mx, lrelu(y));
    }
    hs[b][idx] = mx;
  }
  __syncthreads();

  int ol = t & 63, b = t >> 6;
  int o = ot * 64 + ol;
  int oc_ = o < 600 ? o : 599;
  const float* wb = w + (size_t)(ich * 64) * 600 + oc_;
  float a0 = 0.f, a1 = 0.f, a2 = 0.f, a3 = 0.f;
#pragma unroll 4
  for (int i = 0; i < 64; i += 4) {
    a0 = fmaf(hs[b][i], wb[(size_t)i * 600], a0);
    a1 = fmaf(hs[b][i + 1], wb[(size_t)(i + 1) * 600], a1);
    a2 = fmaf(hs[b][i + 2], wb[(size_t)(i + 2) * 600], a2);
    a3 = fmaf(hs[b][i + 3], wb[(size_t)(i + 3) * 600], a3);
  }
  if (o < 600) f1p[((size_t)ich * 4 + b) * 600 + o] = a0 + a1 + a2 + a3;
}

__global__ __launch_bounds__(256) void k_fc2(const float* __restrict__ f1p,
                                             const float* __restrict__ fc1b,
                                             const float* __restrict__ w,
                                             float* __restrict__ f2p) {
  int blk = blockIdx.x;
  int is = blk & 7, ot = blk >> 3;
  __shared__ float h1s[4][76];
  int t = threadIdx.x;
  for (int e = t; e < 300; e += 256) {
    int bb = e / 75, ii = e % 75;
    int i = is * 75 + ii;
    float s = fc1b[i];
#pragma unroll
    for (int ich = 0; ich < 32; ++ich) s += f1p[((size_t)ich * 4 + bb) * 600 + i];
    h1s[bb][ii] = lrelu(s);
  }
  __syncthreads();
  int ol = t & 63, b = t >> 6;
  int o = ot * 64 + ol, oc_ = o < 300 ? o : 299;
  const float* wb = w + (size_t)(is * 75) * 300 + oc_;
  float a0 = 0.f, a1 = 0.f, a2 = 0.f;
#pragma unroll 5
  for (int ii = 0; ii < 75; ii += 3) {
    a0 = fmaf(h1s[b][ii], wb[(size_t)ii * 300], a0);
    a1 = fmaf(h1s[b][ii + 1], wb[(size_t)(ii + 1) * 300], a1);
    a2 = fmaf(h1s[b][ii + 2], wb[(size_t)(ii + 2) * 300], a2);
  }
  if (o < 300) f2p[((size_t)is * 4 + b) * 300 + o] = a0 + a1 + a2;
}

__global__ __launch_bounds__(1024) void k_fc3f(const float* __restrict__ f2p,
                                               const float* __restrict__ fc2b,
                                               const float* __restrict__ w3,
                                               const float* __restrict__ fc3b,
                                               float* __restrict__ out) {
  __shared__ float h2s[4][304];
  int t = threadIdx.x;
  for (int e = t; e < 1200; e += 1024) {
    int o = e % 300, b = e / 300;
    float s = fc2b[o];
#pragma unroll
    for (int is = 0; is < 8; ++is) s += f2p[((size_t)is * 4 + b) * 300 + o];
    h2s[b][o] = lrelu(s);
  }
  __syncthreads();
  int wv = t >> 6, l = t & 63;
  if (wv < 4) {
    float s = 0.f;
#pragma unroll
    for (int m = 0; m < 5; ++m) {
      int i = m * 64 + l;
      if (i < 300) s = fmaf(h2s[wv][i], w3[i], s);
    }
    for (int off = 32; off; off >>= 1) s += __shfl_down(s, off, 64);
    if (l == 0) out[262144 + wv] = s + fc3b[0];
  }
}

extern "C" void kernel_launch(void* const* d_in, const int* in_sizes, int n_in,
                              void* d_out, int out_size, void* d_ws, size_t ws_size,
                              hipStream_t stream) {
  float* ws = (float*)d_ws;
  const int* p1 = (const int*)d_in[0];
  const int* p2 = (const int*)d_in[1];
  const float* emb  = (const float*)d_in[2];
  const float* w0   = (const float*)d_in[3];
  const float* b0   = (const float*)d_in[4];
  const float* w1   = (const float*)d_in[5];
  const float* b1   = (const float*)d_in[6];
  const float* w2   = (const float*)d_in[7];
  const float* b2   = (const float*)d_in[8];
  const float* ja1w = (const float*)d_in[9];
  const float* ja1b = (const float*)d_in[10];
  const float* ja2w = (const float*)d_in[11];
  const float* ja2b = (const float*)d_in[12];
  const float* rcw  = (const float*)d_in[13];
  const float* rcb  = (const float*)d_in[14];
  const float* fc1w = (const float*)d_in[15];
  const float* fc1b = (const float*)d_in[16];
  const float* fc2w = (const float*)d_in[17];
  const float* fc2b = (const float*)d_in[18];
  const float* fc3w = (const float*)d_in[19];
  const float* fc3b = (const float*)d_in[20];
  float* out = (float*)d_out;

  u16* xa  = (u16*)(ws + OFF_XA);
  u16* xb  = (u16*)(ws + OFF_XB);
  u16* wbu = (u16*)(ws + OFF_WB);
  u16* wju = (u16*)(ws + OFF_WJ);
  u16* ebf = (u16*)(ws + OFF_EBF);
  u16* qk  = (u16*)(ws + OFF_QK);

  k_prepall<<<1024, 256, 0, stream>>>(p1, p2, emb, w0, w1, w2, ja1w, ja2w, xa, xb, wbu, wju);

  k_cmf<4, 1, 0><<<512, 256, 0, stream>>>(xa, wbu + WB_L1, b0, xb, nullptr, nullptr);
  k_cmf<8, 3, 0><<<512, 256, 0, stream>>>(xb, wbu + WB_L2, b1, xa, nullptr, nullptr);
  k_cmf<12, 5, 1><<<512, 256, 0, stream>>>(xa, wbu + WB_L3, b2, nullptr, ws + OFF_E, ebf);

  k_jam<<<512, 256, 0, stream>>>(ebf, wju, ja1b, ja2b, qk);
  k_scoresm<<<256, 256, 0, stream>>>(qk, ws + OFF_S, ws + OFF_BS);

  k_pool<<<2048, 256, 0, stream>>>(ws + OFF_E, ws + OFF_E + SZ, ws + OFF_S, ws + OFF_BS,
                                   out, ws + OFF_PP);
  k_poolcomb<<<32, 256, 0, stream>>>(ws + OFF_PP, ws + OFF_POOL);

  k_fc1h<<<320, 256, 0, stream>>>(ws + OFF_POOL, rcw, rcb, fc1w, ws + OFF_F1P);
  k_fc2<<<40, 256, 0, stream>>>(ws + OFF_F1P, fc1b, fc2w, ws + OFF_F2P);
  k_fc3f<<<1, 1024, 0, stream>>>(ws + OFF_F2P, fc2b, fc3w, fc3b, out);
}